// Round 17
// baseline (99.684 us; speedup 1.0000x reference)
//
#include <hip/hip_runtime.h>

#define NEG 5
#define MM 6
#define NCTX 6
#define NC 36
#define DD 128
#define WPB 4
#define RPW 2
#define RPB (WPB * RPW)
#define DROW 12
#define QS 4096.0f
#define INV_S (1.0f / 4096.0f)

#define SB() __builtin_amdgcn_sched_barrier(0)

typedef float v2f __attribute__((ext_vector_type(2)));
typedef float v4f __attribute__((ext_vector_type(4)));

__device__ __forceinline__ int geti(const int4& v, int c) {
    switch (c) { case 0: return v.x; case 1: return v.y; case 2: return v.z; default: return v.w; }
}
__device__ __forceinline__ float getf(const float4& v, int c) {
    switch (c) { case 0: return v.x; case 1: return v.y; case 2: return v.z; default: return v.w; }
}

// ============ emb1 fp32 -> fp8(e4m3, xQS); 2x dwordx4 per iter (R16, ~17us) ============
__global__ __launch_bounds__(256) void cvt_fp8_kernel(
    const float* __restrict__ emb1, unsigned int* __restrict__ q, long n4)
{
    const long stride = (long)gridDim.x * 512;
    for (long i0 = (long)blockIdx.x * 512 + threadIdx.x; i0 < n4; i0 += stride) {
        const long i1 = i0 + 256;
        v4f a = __builtin_nontemporal_load(reinterpret_cast<const v4f*>(emb1) + i0);
        int ra = 0;
        ra = __builtin_amdgcn_cvt_pk_fp8_f32(a[0] * QS, a[1] * QS, ra, false);
        ra = __builtin_amdgcn_cvt_pk_fp8_f32(a[2] * QS, a[3] * QS, ra, true);
        q[i0] = (unsigned int)ra;
        if (i1 < n4) {
            v4f b = __builtin_nontemporal_load(reinterpret_cast<const v4f*>(emb1) + i1);
            int rb = 0;
            rb = __builtin_amdgcn_cvt_pk_fp8_f32(b[0] * QS, b[1] * QS, rb, false);
            rb = __builtin_amdgcn_cvt_pk_fp8_f32(b[2] * QS, b[3] * QS, rb, true);
            q[i1] = (unsigned int)rb;
        }
    }
}

// ============ fused kernel: R8 configuration verbatim (72us measured) ============
template<int J>
__device__ __forceinline__ void issue_ctx8(unsigned int* dst, const int4& ci, int base,
                                           const unsigned int* __restrict__ q, int sl) {
    #pragma unroll
    for (int m = 0; m < MM; ++m) {
        const int flat = J * MM + m;
        const int k = flat >> 2, c = flat & 3;
        const int idx = __shfl(geti(ci, c), base + k, 64);
        dst[m] = q[(size_t)idx * 32 + sl];
    }
}

template<int J>
__device__ __forceinline__ float consume_dot8(const unsigned int* src, const float4& cmk,
                                              int base, const float4& w) {
    float pj = 0.f;
    #pragma unroll
    for (int m = 0; m < MM; ++m) {
        const int flat = J * MM + m;
        const int k = flat >> 2, c = flat & 3;
        const float mk = __shfl(getf(cmk, c), base + 9 + k, 64);
        v2f lo = __builtin_amdgcn_cvt_pk_f32_fp8(src[m], false);
        v2f hi = __builtin_amdgcn_cvt_pk_f32_fp8(src[m], true);
        pj += mk * (lo[0] * w.x + lo[1] * w.y + hi[0] * w.z + hi[1] * w.w);
    }
    return pj;
}

__global__ __launch_bounds__(256) void sg_fused8_kernel(
    const int*   __restrict__ data,
    const int*   __restrict__ w2m,
    const float* __restrict__ w2m_mask,
    const int*   __restrict__ c2m,
    const float* __restrict__ c2m_mask,
    const float* __restrict__ emb0,
    const unsigned int* __restrict__ q,   // emb1 fp8, 32 uints/row
    float*       __restrict__ out,
    int B)
{
    const int lane  = threadIdx.x & 63;
    const int wid   = threadIdx.x >> 6;
    const int sub   = lane >> 5;
    const int slane = lane & 31;
    const int base  = lane & 32;
    const int b     = blockIdx.x * RPB + wid * RPW + sub;

    float loss = 0.0f;
    if (b < B) {
        int4 ci = {0,0,0,0}; float4 cmk = {0.f,0.f,0.f,0.f};
        int wi = 0; float wmk = 0.f; int nm = 0;
        if (slane < 9)       ci  = reinterpret_cast<const int4*>(c2m + (size_t)b * NC)[slane];
        else if (slane < 18) cmk = reinterpret_cast<const float4*>(c2m_mask + (size_t)b * NC)[slane - 9];
        else if (slane < 24) wi  = w2m[(size_t)b * MM + (slane - 18)];
        else if (slane < 30) wmk = w2m_mask[(size_t)b * MM + (slane - 24)];
        if (slane < NEG) nm = data[(size_t)b * DROW + 2 + NEG + slane];

        float nmf[NEG];
        #pragma unroll
        for (int n = 0; n < NEG; ++n) nmf[n] = (float)__shfl(nm, base + n, 64);

        const int d0 = slane * 4;

        // word gathers (fp32 emb0) + all 6 fp8 ctx bufs in flight
        float4 wr[MM];
        #pragma unroll
        for (int m = 0; m < MM; ++m) {
            const int idx = __shfl(wi, base + 18 + m, 64);
            wr[m] = *reinterpret_cast<const float4*>(emb0 + (size_t)idx * DD + d0);
        }
        unsigned int A8[MM], B8[MM], C8[MM], D8[MM], E8[MM], F8[MM];
        issue_ctx8<0>(A8, ci, base, q, slane);
        issue_ctx8<1>(B8, ci, base, q, slane);
        issue_ctx8<2>(C8, ci, base, q, slane);
        issue_ctx8<3>(D8, ci, base, q, slane);
        issue_ctx8<4>(E8, ci, base, q, slane);
        issue_ctx8<5>(F8, ci, base, q, slane);
        SB();

        float4 w = {0.f,0.f,0.f,0.f};
        #pragma unroll
        for (int m = 0; m < MM; ++m) {
            const float mk = __shfl(wmk, base + 24 + m, 64);
            w.x += wr[m].x * mk; w.y += wr[m].y * mk;
            w.z += wr[m].z * mk; w.w += wr[m].w * mk;
        }
        w.x *= INV_S; w.y *= INV_S; w.z *= INV_S; w.w *= INV_S;

        float p[NCTX];
        p[0] = consume_dot8<0>(A8, cmk, base, w);
        p[1] = consume_dot8<1>(B8, cmk, base, w);
        p[2] = consume_dot8<2>(C8, cmk, base, w);
        p[3] = consume_dot8<3>(D8, cmk, base, w);
        p[4] = consume_dot8<4>(E8, cmk, base, w);
        p[5] = consume_dot8<5>(F8, cmk, base, w);

        #pragma unroll
        for (int j = 0; j < NCTX; ++j) {
            float v = p[j];
            #pragma unroll
            for (int off = 16; off >= 1; off >>= 1) v += __shfl_xor(v, off, 64);
            p[j] = v;
        }
        if (slane == 0) {
            float x = fminf(fmaxf(p[0], -10.0f), 10.0f);
            loss = log1pf(expf(-x));
            #pragma unroll
            for (int n = 0; n < NEG; ++n) {
                float y = fminf(fmaxf(-p[1 + n], -10.0f), 10.0f);
                loss += log1pf(expf(-y)) * nmf[n];
            }
        }
    }
    __shared__ float sacc[RPB];
    if (slane == 0) sacc[wid * RPW + sub] = loss;
    __syncthreads();
    if (threadIdx.x == 0) {
        float s = 0.0f;
        #pragma unroll
        for (int i = 0; i < RPB; ++i) s += sacc[i];
        atomicAdd(out, s);
    }
}

extern "C" void kernel_launch(void* const* d_in, const int* in_sizes, int n_in,
                              void* d_out, int out_size, void* d_ws, size_t ws_size,
                              hipStream_t stream) {
    const int*   data     = (const int*)  d_in[0];
    const int*   w2m      = (const int*)  d_in[1];
    const float* w2m_mask = (const float*)d_in[2];
    const int*   c2m      = (const int*)  d_in[3];
    const float* c2m_mask = (const float*)d_in[4];
    const float* emb0     = (const float*)d_in[5];
    const float* emb1     = (const float*)d_in[6];
    float* out = (float*)d_out;

    const int B     = in_sizes[1] / MM;
    const int vocab = in_sizes[6] / DD;
    const int blocks = (B + RPB - 1) / RPB;
    const long n4   = (long)vocab * 32;

    (void)hipMemsetAsync(out, 0, sizeof(float), stream);

    unsigned int* q = (unsigned int*)d_ws;        // fp8 table, vocab*128 B
    cvt_fp8_kernel<<<4096, 256, 0, stream>>>(emb1, q, n4);
    sg_fused8_kernel<<<blocks, 64 * WPB, 0, stream>>>(
        data, w2m, w2m_mask, c2m, c2m_mask, emb0, q, out, B);
}